// Round 22
// baseline (65.065 us; speedup 1.0000x reference)
//
#include <hip/hip_runtime.h>
#include <stdint.h>

#define NLOC 469
#define NCLS 80
#define NFLAT 37520
#define TOPK 1000
#define NB 512           // compact hist: valid bin (o>>17) in [24230,24511] subset of [BOFF,BOFF+511]
#define BOFF 24192
#define CAP 2048         // candidate capacity

typedef unsigned long long u64;

__device__ __forceinline__ float sigm(float x) { return 1.0f / (1.0f + expf(-x)); }

// order-preserving float -> uint32 (greater float => greater uint)
__device__ __forceinline__ uint32_t f2o(float f) {
    uint32_t u = __float_as_uint(f);
    return (u & 0x80000000u) ? ~u : (u | 0x80000000u);
}

// ---- single kernel: decode + top-k + pair-symmetric NMS + output (1 block)
__global__ void __launch_bounds__(1024, 4) mono_kernel(
    const float* __restrict__ s0, const float* __restrict__ l0, const float* __restrict__ c0,
    const float* __restrict__ s1, const float* __restrict__ l1, const float* __restrict__ c1,
    const float* __restrict__ s2, const float* __restrict__ l2, const float* __restrict__ c2,
    float* __restrict__ out)
{
    // overlay: A uses histW(32K)@0 + histS@65536 + candL(16K)@69632 + bboxL@86016;
    //          C uses smask 128000 B @0 (bboxL consumed before the zero)
    __shared__ __align__(16) unsigned char ubuf[131072];
    int*      histW = (int*)ubuf;                    // 16*512 ints
    int*      histS = (int*)(ubuf + 65536);          // 512 ints
    u64*      candL = (u64*)(ubuf + 69632);          // 2048 u64
    float4*   bboxL = (float4*)(ubuf + 86016);       // 469 float4 = 7504 B
    uint32_t* smask = (uint32_t*)ubuf;               // 32000 u32 (phase C)

    __shared__ float4 sboxL[TOPK];                  // 16000 B
    __shared__ float tvalL[TOPK];
    __shared__ int   tidxL[TOPK];
    __shared__ unsigned char lab8[TOPK];
    __shared__ unsigned char zrow[TOPK];
    __shared__ unsigned short csorted[TOPK];
    __shared__ int clsStart[NCLS], clsCur[NCLS];
    __shared__ uint32_t skeep32[32], validw32[32], zmaskL[32];
    __shared__ float redMax[16], redMin[16];
    __shared__ float Mp1_s;
    __shared__ int dmax_s;
    __shared__ int bstar_s;

    int tid = threadIdx.x;
    int lane = tid & 63, wv = tid >> 6;

    // ---- D: decode scores directly into registers (37520 = 36*1024 + 656)
    const int nw = (tid < 656) ? 37 : 36;
    uint32_t vbuf[37];
    #pragma unroll
    for (int k = 0; k < 37; ++k) {
        vbuf[k] = 0u;
        int t = tid + (k << 10);
        if (t < NFLAT) {
            int p = t / NCLS;
            int kk = t - p * NCLS;
            int c = kk + 1;                  // class channel (0 = background, dropped)
            const float* sr; const float* cr; int local, hw;
            if (p < 350)      { sr = s0; cr = c0; local = p;       hw = 350; }
            else if (p < 441) { sr = s1; cr = c1; local = p - 350; hw = 91;  }
            else              { sr = s2; cr = c2; local = p - 441; hw = 28;  }
            float val = sqrtf(sigm(sr[c * hw + local]) * sigm(cr[local]));
            if (val >= 0.05f) vbuf[k] = f2o(val);
        }
    }
    // decode bboxes into LDS (469 locations)
    if (tid < NLOC) {
        int p = tid;
        const float* lr; int local, hw, w; float is;
        if (p < 350)      { lr = l0; local = p;       hw = 350; w = 25; is = 16.0f; }
        else if (p < 441) { lr = l1; local = p - 350; hw = 91;  w = 13; is = 32.0f; }
        else              { lr = l2; local = p - 441; hw = 28;  w = 7;  is = 64.0f; }
        int y = local / w, x = local - y * w;
        float px = ((float)x + 0.5f) * is;
        float py = ((float)y + 0.5f) * is;
        float L = lr[local] * is;
        float T = lr[hw + local] * is;
        float R = lr[2 * hw + local] * is;
        float B = lr[3 * hw + local] * is;
        bboxL[p] = make_float4(px - L, py - T, px + R, py + B);
    }
    if (tid == 0) bstar_s = 0;
    if (tid < TOPK) { tvalL[tid] = -1.0f; tidxL[tid] = 0; }
    for (int z = tid; z < 16 * NB; z += 1024) histW[z] = 0;
    __syncthreads();
    // ---- A2: per-wave hist build from registers (valid-only; 0 skipped)
    int* myh = &histW[wv * NB];
    #pragma unroll
    for (int k = 0; k < 37; ++k) {
        if (k < nw) {
            uint32_t o = vbuf[k];
            if (o) atomicAdd(&myh[(o >> 17) - BOFF], 1);
        }
    }
    __syncthreads();
    // ---- A2b: reduce 16 sub-hists
    if (tid < NB) {
        int s = 0;
        #pragma unroll
        for (int w = 0; w < 16; ++w) s += histW[w * NB + tid];
        histS[tid] = s;
    }
    __syncthreads();
    // ---- A3: single-wave select over 512 bins
    if (tid < 64) {
        int bs = NB - 8 * (tid + 1);                // lane 0 owns HIGHEST 8 bins
        int h[8];
        int s = 0;
        #pragma unroll
        for (int k = 0; k < 8; ++k) { h[k] = histS[bs + k]; s += h[k]; }
        int ws = s;
        #pragma unroll
        for (int d = 1; d < 64; d <<= 1) {
            int v = __shfl_up(ws, d, 64);
            if (tid >= d) ws += v;
        }
        int cumAbove = ws - s;
        if (cumAbove < TOPK && ws >= TOPK) {        // exactly one lane crosses
            int running = cumAbove;
            #pragma unroll
            for (int k = 7; k >= 0; --k) {
                if (running + h[k] >= TOPK) { bstar_s = BOFF + bs + k; break; }
                running += h[k];
            }
        }
        int run = cumAbove;                         // starts, descending bin-major
        #pragma unroll
        for (int k = 7; k >= 0; --k) { histS[bs + k] = run; run += h[k]; }
    }
    __syncthreads();
    int Bstar = bstar_s;
    // ---- A4: counting-sort scatter; key rebuilt from register o and t
    #pragma unroll
    for (int k = 0; k < 37; ++k) {
        if (k < nw) {
            uint32_t o = vbuf[k];
            int b = (int)(o >> 17);
            if (o && b >= Bstar) {
                int t = tid + (k << 10);
                int pos = atomicAdd(&histS[b - BOFF], 1);
                if (pos < CAP)
                    candL[pos] = ((u64)o << 32) | (u64)(0xFFFFFFFFu - (uint32_t)t);
            }
        }
    }
    __syncthreads();
    int C = min(histS[Bstar - BOFF], CAP);          // end(Bstar) == candidate count
    // ---- A5: exact rank within bin segment -> tvalL/tidxL (LDS)
    for (int p = tid; p < C; p += 1024) {
        u64 kk = candL[p];
        int bidx = (int)(kk >> 49) - BOFF;
        int segL = (bidx == NB - 1) ? 0 : min(histS[bidx + 1], CAP);
        int segR = min(histS[bidx], CAP);
        int cnt = segL;
        for (int q = segL; q < segR; ++q)
            cnt += (candL[q] > kk) ? 1 : 0;
        if (cnt < TOPK) {
            uint32_t o = (uint32_t)(kk >> 32);
            uint32_t u = (o & 0x80000000u) ? (o ^ 0x80000000u) : ~o;  // inverse f2o
            tvalL[cnt] = __uint_as_float(u);
            tidxL[cnt] = (int)(0xFFFFFFFFu - (uint32_t)(kk & 0xFFFFFFFFu));
        }
    }
    __syncthreads();

    // ---- C: NMS (r18/r19-proven). Gather per-thread state from LDS.
    float tvR = (tid < TOPK) ? tvalL[tid] : -1.0f;
    int   idxR = (tid < TOPK) ? tidxL[tid] : 0;
    int   pR = idxR / NCLS;
    int   labR = idxR - pR * NCLS;
    float4 bR = make_float4(0.f, 0.f, 0.f, 0.f);
    if (tid < TOPK) bR = bboxL[pR];
    __syncthreads();                         // all bboxL reads done before ubuf overlay

    // C1a: zero smask (vectorized, overwrites A's ubuf incl. bboxL) + zrow
    {
        uint4* z4 = (uint4*)smask;
        for (int z = tid; z < TOPK * 8; z += 1024) z4[z] = make_uint4(0, 0, 0, 0);
    }
    if (tid < TOPK) zrow[tid] = 0;
    float m = -3.0e38f, lmin = 3.0e38f;
    if (tid < TOPK) {
        sboxL[tid] = bR;                     // raw for now
        lab8[tid] = (unsigned char)labR;
        m = fmaxf(fmaxf(bR.x, bR.y), fmaxf(bR.z, bR.w));
        lmin = fminf(bR.x, bR.y);
    }
    for (int o = 32; o > 0; o >>= 1) {
        m = fmaxf(m, __shfl_down(m, o, 64));
        lmin = fminf(lmin, __shfl_down(lmin, o, 64));
    }
    if (lane == 0) { redMax[wv] = m; redMin[wv] = lmin; }
    if (tid < NCLS) clsCur[tid] = 0;
    __syncthreads();
    if (tid == 0) {
        float mm = redMax[0], ll = redMin[0];
        for (int q = 1; q < 16; ++q) { mm = fmaxf(mm, redMax[q]); ll = fminf(ll, redMin[q]); }
        float Mp1 = mm + 1.0f;
        Mp1_s = Mp1;
        int dm = 79;
        if (Mp1 > 0.0f) {
            float ratio = (mm - ll) / Mp1;
            dm = (int)ceilf(ratio);
            if (dm < 0) dm = 0;
            if (dm > 79) dm = 79;
        }
        dmax_s = dm;
    }
    __syncthreads();
    // C1b: apply class offset in place; count classes
    float Mp1 = Mp1_s;
    if (tid < TOPK) {
        float off = (float)labR * Mp1;
        sboxL[tid] = make_float4(bR.x + off, bR.y + off, bR.z + off, bR.w + off);
        atomicAdd(&clsCur[labR], 1);
    }
    __syncthreads();
    // C2: single-wave exclusive scan of 80 class counts
    if (tid < 64) {
        int l = tid;
        int e0 = clsCur[l];
        int e1 = (l < 16) ? clsCur[64 + l] : 0;
        int s = e0;
        for (int d = 1; d < 64; d <<= 1) {
            int v = __shfl_up(s, d, 64);
            if (l >= d) s += v;
        }
        int tot64 = __shfl(s, 63, 64);
        int s2 = e1;
        for (int d = 1; d < 16; d <<= 1) {
            int v = __shfl_up(s2, d, 64);
            if (l >= d) s2 += v;
        }
        int ex0 = s - e0;
        clsStart[l] = ex0;
        clsCur[l] = ex0;
        if (l < 16) {
            int ex1 = tot64 + s2 - e1;
            clsStart[64 + l] = ex1;
            clsCur[64 + l] = ex1;
        }
    }
    __syncthreads();
    if (tid < TOPK) {
        int pos = atomicAdd(&clsCur[labR], 1);
        csorted[pos] = (unsigned short)tid;
    }
    __syncthreads();                         // clsCur[c] is now END of class c
    // C3: pair-symmetric IoU — each unordered pair computed exactly once
    if (tid < TOPK) {
        int s = tid;
        int i = csorted[s];
        int c = lab8[i];
        float4 si = sboxL[i];
        float ai = fmaxf(si.z - si.x, 0.f) * fmaxf(si.w - si.y, 0.f);
        int chi = c + dmax_s; if (chi > NCLS - 1) chi = NCLS - 1;
        int endPos = clsCur[chi];            // contiguous end through class chi
        for (int t = s + 1; t < endPos; ++t) {
            int j = csorted[t];
            float4 sj = sboxL[j];
            float aj = fmaxf(sj.z - sj.x, 0.f) * fmaxf(sj.w - sj.y, 0.f);
            float ltx = fmaxf(si.x, sj.x), lty = fmaxf(si.y, sj.y);
            float rbx = fminf(si.z, sj.z), rby = fminf(si.w, sj.w);
            float iw = fmaxf(rbx - ltx, 0.f), ih = fmaxf(rby - lty, 0.f);
            float inter = iw * ih;
            float iou = inter / fmaxf(ai + aj - inter, 1e-9f);
            if (iou > 0.6f) {
                int lo = min(i, j), hi = max(i, j);
                atomicOr(&smask[lo * 32 + (hi >> 5)], 1u << (hi & 31));
                zrow[lo] = 1;                // benign race: all writers store 1
            }
        }
    }
    __syncthreads();
    // zmask + validw ballots (row-indexed)
    {
        u64 zb = __ballot(tid < TOPK && zrow[tid] != 0);
        if (lane == 0) {
            zmaskL[wv * 2]     = (uint32_t)zb;
            zmaskL[wv * 2 + 1] = (uint32_t)(zb >> 32);
        }
        u64 bal = __ballot(tid < TOPK && tvR >= 0.05f);
        if (lane == 0) {
            validw32[wv * 2]     = (uint32_t)bal;
            validw32[wv * 2 + 1] = (uint32_t)(bal >> 32);
        }
    }
    __syncthreads();
    // C4: sparse greedy scan (single wave, 3-deep rotating prefetch)
    if (tid < 32) {
        const int ln = tid;
        uint32_t vwreg = validw32[ln];
        uint32_t zreg  = zmaskL[ln];
        uint32_t sup = 0;
        for (int wc = 0; wc < 32; ++wc) {
            uint32_t nzw = (uint32_t)__builtin_amdgcn_readlane((int)zreg, wc);
            uint32_t avail = (uint32_t)__builtin_amdgcn_readlane((int)vwreg, wc)
                           & ~(uint32_t)__builtin_amdgcn_readlane((int)sup, wc);
            int p0 = -1, p1 = -1, p2 = -1;
            uint32_t R0 = 0, R1 = 0, R2 = 0;
            if (nzw) { p0 = __ffs(nzw) - 1; nzw &= nzw - 1;
                       R0 = smask[(wc * 32 + p0) * 32 + ln]; }
            if (nzw) { p1 = __ffs(nzw) - 1; nzw &= nzw - 1;
                       R1 = smask[(wc * 32 + p1) * 32 + ln]; }
            if (nzw) { p2 = __ffs(nzw) - 1; nzw &= nzw - 1;
                       R2 = smask[(wc * 32 + p2) * 32 + ln]; }
            while (p0 >= 0) {
                uint32_t rc = (uint32_t)__builtin_amdgcn_readlane((int)R0, wc);
                uint32_t kp = (avail >> p0) & 1u;
                uint32_t mm = 0u - kp;
                sup   |= R0 & mm;
                avail &= ~(rc & mm);
                p0 = p1; R0 = R1; p1 = p2; R1 = R2;
                if (nzw) { p2 = __ffs(nzw) - 1; nzw &= nzw - 1;
                           R2 = smask[(wc * 32 + p2) * 32 + ln]; }
                else p2 = -1;
            }
            if (ln == 0) skeep32[wc] = avail;   // frozen == final keep bits
        }
    }
    __syncthreads();
    // C5: clip + output (bR/tvR/labR live in registers)
    if (tid < TOPK) {
        bool kp = (skeep32[tid >> 5] >> (tid & 31)) & 1u;
        float x1 = fminf(fmaxf(bR.x, 0.f), 224.f);
        float y1 = fminf(fmaxf(bR.y, 0.f), 398.f);
        float x2 = fminf(fmaxf(bR.z, 0.f), 224.f);
        float y2 = fminf(fmaxf(bR.w, 0.f), 398.f);
        kp = kp && ((x2 - x1) >= 1e-5f) && ((y2 - y1) >= 1e-5f);
        out[tid * 4 + 0] = kp ? x1 : 0.f;
        out[tid * 4 + 1] = kp ? y1 : 0.f;
        out[tid * 4 + 2] = kp ? x2 : 0.f;
        out[tid * 4 + 3] = kp ? y2 : 0.f;
        out[4 * TOPK + tid] = kp ? tvR : -1.0f;
        out[5 * TOPK + tid] = (float)labR;
        out[6 * TOPK + tid] = kp ? 1.0f : 0.0f;
    }
}

extern "C" void kernel_launch(void* const* d_in, const int* in_sizes, int n_in,
                              void* d_out, int out_size, void* d_ws, size_t ws_size,
                              hipStream_t stream)
{
    const float* s0 = (const float*)d_in[0];
    const float* l0 = (const float*)d_in[1];
    const float* c0 = (const float*)d_in[2];
    const float* s1 = (const float*)d_in[3];
    const float* l1 = (const float*)d_in[4];
    const float* c1 = (const float*)d_in[5];
    const float* s2 = (const float*)d_in[6];
    const float* l2 = (const float*)d_in[7];
    const float* c2 = (const float*)d_in[8];

    mono_kernel<<<1, 1024, 0, stream>>>(
        s0, l0, c0, s1, l1, c1, s2, l2, c2, (float*)d_out);
}

// Round 23
// 48.004 us; speedup vs baseline: 1.3554x; 1.3554x over previous
//
#include <hip/hip_runtime.h>
#include <stdint.h>

#define NLOC 469
#define NCLS 80
#define NFLAT 37520
#define TOPK 1000
#define NB 512           // compact hist: valid bin (o>>17) in [24230,24511] subset of [BOFF,BOFF+511]
#define BOFF 24192
#define CAP 2048         // candidate capacity
#define NBLK 147         // decode blocks (147*256 >= 37520)

typedef unsigned long long u64;

__device__ __forceinline__ float sigm(float x) { return 1.0f / (1.0f + expf(-x)); }

// order-preserving float -> uint32 (greater float => greater uint)
__device__ __forceinline__ uint32_t f2o(float f) {
    uint32_t u = __float_as_uint(f);
    return (u & 0x80000000u) ? ~u : (u | 0x80000000u);
}

// ---------------- K1: decode (parallel, 147 blocks; r19-proven)
__global__ void decode_kernel(
    const float* __restrict__ s0, const float* __restrict__ l0, const float* __restrict__ c0,
    const float* __restrict__ s1, const float* __restrict__ l1, const float* __restrict__ c1,
    const float* __restrict__ s2, const float* __restrict__ l2, const float* __restrict__ c2,
    uint32_t* __restrict__ o32, float4* __restrict__ bbox)
{
    int t = blockIdx.x * blockDim.x + threadIdx.x;
    if (t < NFLAT) {
        int p = t / NCLS;
        int k = t - p * NCLS;
        int c = k + 1;                       // class channel (0 = background, dropped)
        const float* sr; const float* cr; int local, hw;
        if (p < 350)      { sr = s0; cr = c0; local = p;       hw = 350; }
        else if (p < 441) { sr = s1; cr = c1; local = p - 350; hw = 91;  }
        else              { sr = s2; cr = c2; local = p - 441; hw = 28;  }
        float val = sqrtf(sigm(sr[c * hw + local]) * sigm(cr[local]));
        bool valid = (val >= 0.05f);
        // valid o in [f2o(0.05), f2o(1)) -> bin (o>>17) in [24230, 24511]
        o32[t] = valid ? f2o(val) : 0u;
    }
    if (t < NLOC) {
        int p = t;
        const float* lr; int local, hw, w; float is;
        if (p < 350)      { lr = l0; local = p;       hw = 350; w = 25; is = 16.0f; }
        else if (p < 441) { lr = l1; local = p - 350; hw = 91;  w = 13; is = 32.0f; }
        else              { lr = l2; local = p - 441; hw = 28;  w = 7;  is = 64.0f; }
        int y = local / w, x = local - y * w;
        float px = ((float)x + 0.5f) * is;
        float py = ((float)y + 0.5f) * is;
        float L = lr[local] * is;
        float T = lr[hw + local] * is;
        float R = lr[2 * hw + local] * is;
        float B = lr[3 * hw + local] * is;
        bbox[p] = make_float4(px - L, py - T, px + R, py + B);
    }
}

// ---------- K2: fused top-k (A) + pair-symmetric NMS (C), one 1024-thread block
// r19-proven; A0/A2/A4 use paired uint2 prefetch (half the load instructions)
__global__ void __launch_bounds__(1024, 4) fused_kernel(
    const uint32_t* __restrict__ o32, const float4* __restrict__ bbox,
    float* __restrict__ out)
{
    // overlay: A uses histW(32K)+histS(2K)+candL(16K) = 50K; C uses smask 128K
    __shared__ __align__(16) unsigned char ubuf[131072];
    int*      histW = (int*)ubuf;                    // 16*512 ints
    int*      histS = (int*)(ubuf + 65536);          // 512 ints
    u64*      candL = (u64*)(ubuf + 69632);          // 2048 u64
    uint32_t* smask = (uint32_t*)ubuf;               // 32000 u32 (phase C)

    __shared__ float4 sboxL[TOPK];                  // 16000 B
    __shared__ float tvalL[TOPK];
    __shared__ int   tidxL[TOPK];
    __shared__ unsigned char lab8[TOPK];
    __shared__ unsigned char zrow[TOPK];
    __shared__ unsigned short csorted[TOPK];
    __shared__ int clsStart[NCLS], clsCur[NCLS];
    __shared__ uint32_t skeep32[32], validw32[32], zmaskL[32];
    __shared__ float redMax[16], redMin[16];
    __shared__ float Mp1_s;
    __shared__ int dmax_s;
    __shared__ int bstar_s;

    int tid = threadIdx.x;
    int lane = tid & 63, wv = tid >> 6;

    // ---- A0: paired register prefetch (18760 uint2 = 18*1024 + 328)
    const uint2* o2 = (const uint2*)o32;
    const int nw = (tid < 328) ? 19 : 18;
    uint2 vbuf[19];
    #pragma unroll
    for (int k = 0; k < 19; ++k) {
        int t = tid + (k << 10);
        if (t < NFLAT / 2) vbuf[k] = o2[t];
    }
    if (tid == 0) bstar_s = 0;
    if (tid < TOPK) { tvalL[tid] = -1.0f; tidxL[tid] = 0; }
    for (int z = tid; z < 16 * NB; z += 1024) histW[z] = 0;
    __syncthreads();
    // ---- A2: per-wave hist build from registers (valid-only; 0 skipped)
    int* myh = &histW[wv * NB];
    #pragma unroll
    for (int k = 0; k < 19; ++k) {
        if (k < nw) {
            uint32_t oa = vbuf[k].x, ob = vbuf[k].y;
            if (oa) atomicAdd(&myh[(oa >> 17) - BOFF], 1);
            if (ob) atomicAdd(&myh[(ob >> 17) - BOFF], 1);
        }
    }
    __syncthreads();
    // ---- A2b: reduce 16 sub-hists
    if (tid < NB) {
        int s = 0;
        #pragma unroll
        for (int w = 0; w < 16; ++w) s += histW[w * NB + tid];
        histS[tid] = s;
    }
    __syncthreads();
    // ---- A3: single-wave select over 512 bins
    if (tid < 64) {
        int bs = NB - 8 * (tid + 1);                // lane 0 owns HIGHEST 8 bins
        int h[8];
        int s = 0;
        #pragma unroll
        for (int k = 0; k < 8; ++k) { h[k] = histS[bs + k]; s += h[k]; }
        int ws = s;
        #pragma unroll
        for (int d = 1; d < 64; d <<= 1) {
            int v = __shfl_up(ws, d, 64);
            if (tid >= d) ws += v;
        }
        int cumAbove = ws - s;
        if (cumAbove < TOPK && ws >= TOPK) {        // exactly one lane crosses
            int running = cumAbove;
            #pragma unroll
            for (int k = 7; k >= 0; --k) {
                if (running + h[k] >= TOPK) { bstar_s = BOFF + bs + k; break; }
                running += h[k];
            }
        }
        int run = cumAbove;                         // starts, descending bin-major
        #pragma unroll
        for (int k = 7; k >= 0; --k) { histS[bs + k] = run; run += h[k]; }
    }
    __syncthreads();
    int Bstar = bstar_s;
    // ---- A4: counting-sort scatter; keys rebuilt from register pair and t
    #pragma unroll
    for (int k = 0; k < 19; ++k) {
        if (k < nw) {
            uint32_t oa = vbuf[k].x, ob = vbuf[k].y;
            int t0 = (tid + (k << 10)) * 2;
            if (oa && (int)(oa >> 17) >= Bstar) {
                int pos = atomicAdd(&histS[(int)(oa >> 17) - BOFF], 1);
                if (pos < CAP)
                    candL[pos] = ((u64)oa << 32) | (u64)(0xFFFFFFFFu - (uint32_t)t0);
            }
            if (ob && (int)(ob >> 17) >= Bstar) {
                int pos = atomicAdd(&histS[(int)(ob >> 17) - BOFF], 1);
                if (pos < CAP)
                    candL[pos] = ((u64)ob << 32) | (u64)(0xFFFFFFFFu - (uint32_t)(t0 + 1));
            }
        }
    }
    __syncthreads();
    int C = min(histS[Bstar - BOFF], CAP);          // end(Bstar) == candidate count
    // ---- A5: exact rank within bin segment -> tvalL/tidxL (LDS)
    for (int p = tid; p < C; p += 1024) {
        u64 kk = candL[p];
        int bidx = (int)(kk >> 49) - BOFF;
        int segL = (bidx == NB - 1) ? 0 : min(histS[bidx + 1], CAP);
        int segR = min(histS[bidx], CAP);
        int cnt = segL;
        for (int q = segL; q < segR; ++q)
            cnt += (candL[q] > kk) ? 1 : 0;
        if (cnt < TOPK) {
            uint32_t o = (uint32_t)(kk >> 32);
            uint32_t u = (o & 0x80000000u) ? (o ^ 0x80000000u) : ~o;  // inverse f2o
            tvalL[cnt] = __uint_as_float(u);
            tidxL[cnt] = (int)(0xFFFFFFFFu - (uint32_t)(kk & 0xFFFFFFFFu));
        }
    }
    __syncthreads();

    // ---- C: NMS (r18/r19-proven). Load per-thread state from LDS.
    float tvR = (tid < TOPK) ? tvalL[tid] : -1.0f;
    int   idxR = (tid < TOPK) ? tidxL[tid] : 0;
    int   pR = idxR / NCLS;
    int   labR = idxR - pR * NCLS;
    float4 bR = make_float4(0.f, 0.f, 0.f, 0.f);
    if (tid < TOPK) bR = bbox[pR];

    // C1a: zero smask (vectorized, overwrites A's ubuf) + zrow
    {
        uint4* z4 = (uint4*)smask;
        for (int z = tid; z < TOPK * 8; z += 1024) z4[z] = make_uint4(0, 0, 0, 0);
    }
    if (tid < TOPK) zrow[tid] = 0;
    float m = -3.0e38f, lmin = 3.0e38f;
    if (tid < TOPK) {
        sboxL[tid] = bR;                     // raw for now
        lab8[tid] = (unsigned char)labR;
        m = fmaxf(fmaxf(bR.x, bR.y), fmaxf(bR.z, bR.w));
        lmin = fminf(bR.x, bR.y);
    }
    for (int o = 32; o > 0; o >>= 1) {
        m = fmaxf(m, __shfl_down(m, o, 64));
        lmin = fminf(lmin, __shfl_down(lmin, o, 64));
    }
    if (lane == 0) { redMax[wv] = m; redMin[wv] = lmin; }
    if (tid < NCLS) clsCur[tid] = 0;
    __syncthreads();
    if (tid == 0) {
        float mm = redMax[0], ll = redMin[0];
        for (int q = 1; q < 16; ++q) { mm = fmaxf(mm, redMax[q]); ll = fminf(ll, redMin[q]); }
        float Mp1 = mm + 1.0f;
        Mp1_s = Mp1;
        int dm = 79;
        if (Mp1 > 0.0f) {
            float ratio = (mm - ll) / Mp1;
            dm = (int)ceilf(ratio);
            if (dm < 0) dm = 0;
            if (dm > 79) dm = 79;
        }
        dmax_s = dm;
    }
    __syncthreads();
    // C1b: apply class offset in place; count classes
    float Mp1 = Mp1_s;
    if (tid < TOPK) {
        float off = (float)labR * Mp1;
        sboxL[tid] = make_float4(bR.x + off, bR.y + off, bR.z + off, bR.w + off);
        atomicAdd(&clsCur[labR], 1);
    }
    __syncthreads();
    // C2: single-wave exclusive scan of 80 class counts
    if (tid < 64) {
        int l = tid;
        int e0 = clsCur[l];
        int e1 = (l < 16) ? clsCur[64 + l] : 0;
        int s = e0;
        for (int d = 1; d < 64; d <<= 1) {
            int v = __shfl_up(s, d, 64);
            if (l >= d) s += v;
        }
        int tot64 = __shfl(s, 63, 64);
        int s2 = e1;
        for (int d = 1; d < 16; d <<= 1) {
            int v = __shfl_up(s2, d, 64);
            if (l >= d) s2 += v;
        }
        int ex0 = s - e0;
        clsStart[l] = ex0;
        clsCur[l] = ex0;
        if (l < 16) {
            int ex1 = tot64 + s2 - e1;
            clsStart[64 + l] = ex1;
            clsCur[64 + l] = ex1;
        }
    }
    __syncthreads();
    if (tid < TOPK) {
        int pos = atomicAdd(&clsCur[labR], 1);
        csorted[pos] = (unsigned short)tid;
    }
    __syncthreads();                         // clsCur[c] is now END of class c
    // C3: pair-symmetric IoU — each unordered pair computed exactly once
    if (tid < TOPK) {
        int s = tid;
        int i = csorted[s];
        int c = lab8[i];
        float4 si = sboxL[i];
        float ai = fmaxf(si.z - si.x, 0.f) * fmaxf(si.w - si.y, 0.f);
        int chi = c + dmax_s; if (chi > NCLS - 1) chi = NCLS - 1;
        int endPos = clsCur[chi];            // contiguous end through class chi
        for (int t = s + 1; t < endPos; ++t) {
            int j = csorted[t];
            float4 sj = sboxL[j];
            float aj = fmaxf(sj.z - sj.x, 0.f) * fmaxf(sj.w - sj.y, 0.f);
            float ltx = fmaxf(si.x, sj.x), lty = fmaxf(si.y, sj.y);
            float rbx = fminf(si.z, sj.z), rby = fminf(si.w, sj.w);
            float iw = fmaxf(rbx - ltx, 0.f), ih = fmaxf(rby - lty, 0.f);
            float inter = iw * ih;
            float iou = inter / fmaxf(ai + aj - inter, 1e-9f);
            if (iou > 0.6f) {
                int lo = min(i, j), hi = max(i, j);
                atomicOr(&smask[lo * 32 + (hi >> 5)], 1u << (hi & 31));
                zrow[lo] = 1;                // benign race: all writers store 1
            }
        }
    }
    __syncthreads();
    // zmask + validw ballots (row-indexed)
    {
        u64 zb = __ballot(tid < TOPK && zrow[tid] != 0);
        if (lane == 0) {
            zmaskL[wv * 2]     = (uint32_t)zb;
            zmaskL[wv * 2 + 1] = (uint32_t)(zb >> 32);
        }
        u64 bal = __ballot(tid < TOPK && tvR >= 0.05f);
        if (lane == 0) {
            validw32[wv * 2]     = (uint32_t)bal;
            validw32[wv * 2 + 1] = (uint32_t)(bal >> 32);
        }
    }
    __syncthreads();
    // C4: sparse greedy scan (single wave, 3-deep rotating prefetch)
    if (tid < 32) {
        const int ln = tid;
        uint32_t vwreg = validw32[ln];
        uint32_t zreg  = zmaskL[ln];
        uint32_t sup = 0;
        for (int wc = 0; wc < 32; ++wc) {
            uint32_t nzw = (uint32_t)__builtin_amdgcn_readlane((int)zreg, wc);
            uint32_t avail = (uint32_t)__builtin_amdgcn_readlane((int)vwreg, wc)
                           & ~(uint32_t)__builtin_amdgcn_readlane((int)sup, wc);
            int p0 = -1, p1 = -1, p2 = -1;
            uint32_t R0 = 0, R1 = 0, R2 = 0;
            if (nzw) { p0 = __ffs(nzw) - 1; nzw &= nzw - 1;
                       R0 = smask[(wc * 32 + p0) * 32 + ln]; }
            if (nzw) { p1 = __ffs(nzw) - 1; nzw &= nzw - 1;
                       R1 = smask[(wc * 32 + p1) * 32 + ln]; }
            if (nzw) { p2 = __ffs(nzw) - 1; nzw &= nzw - 1;
                       R2 = smask[(wc * 32 + p2) * 32 + ln]; }
            while (p0 >= 0) {
                uint32_t rc = (uint32_t)__builtin_amdgcn_readlane((int)R0, wc);
                uint32_t kp = (avail >> p0) & 1u;
                uint32_t mm = 0u - kp;
                sup   |= R0 & mm;
                avail &= ~(rc & mm);
                p0 = p1; R0 = R1; p1 = p2; R1 = R2;
                if (nzw) { p2 = __ffs(nzw) - 1; nzw &= nzw - 1;
                           R2 = smask[(wc * 32 + p2) * 32 + ln]; }
                else p2 = -1;
            }
            if (ln == 0) skeep32[wc] = avail;   // frozen == final keep bits
        }
    }
    __syncthreads();
    // C5: clip + output (bR/tvR/labR live in registers)
    if (tid < TOPK) {
        bool kp = (skeep32[tid >> 5] >> (tid & 31)) & 1u;
        float x1 = fminf(fmaxf(bR.x, 0.f), 224.f);
        float y1 = fminf(fmaxf(bR.y, 0.f), 398.f);
        float x2 = fminf(fmaxf(bR.z, 0.f), 224.f);
        float y2 = fminf(fmaxf(bR.w, 0.f), 398.f);
        kp = kp && ((x2 - x1) >= 1e-5f) && ((y2 - y1) >= 1e-5f);
        out[tid * 4 + 0] = kp ? x1 : 0.f;
        out[tid * 4 + 1] = kp ? y1 : 0.f;
        out[tid * 4 + 2] = kp ? x2 : 0.f;
        out[tid * 4 + 3] = kp ? y2 : 0.f;
        out[4 * TOPK + tid] = kp ? tvR : -1.0f;
        out[5 * TOPK + tid] = (float)labR;
        out[6 * TOPK + tid] = kp ? 1.0f : 0.0f;
    }
}

extern "C" void kernel_launch(void* const* d_in, const int* in_sizes, int n_in,
                              void* d_out, int out_size, void* d_ws, size_t ws_size,
                              hipStream_t stream)
{
    const float* s0 = (const float*)d_in[0];
    const float* l0 = (const float*)d_in[1];
    const float* c0 = (const float*)d_in[2];
    const float* s1 = (const float*)d_in[3];
    const float* l1 = (const float*)d_in[4];
    const float* c1 = (const float*)d_in[5];
    const float* s2 = (const float*)d_in[6];
    const float* l2 = (const float*)d_in[7];
    const float* c2 = (const float*)d_in[8];

    uint8_t* ws = (uint8_t*)d_ws;
    uint32_t* o32  = (uint32_t*)(ws);          // 37520*4 = 150080 B
    float4*   bbox = (float4*)  (ws + 150080); // 469*16  =   7504 B -> 157584 B total

    decode_kernel<<<dim3((NFLAT + 255) / 256), 256, 0, stream>>>(
        s0, l0, c0, s1, l1, c1, s2, l2, c2, o32, bbox);
    fused_kernel<<<1, 1024, 0, stream>>>(o32, bbox, (float*)d_out);
}

// Round 24
// 46.143 us; speedup vs baseline: 1.4101x; 1.0403x over previous
//
#include <hip/hip_runtime.h>
#include <stdint.h>

#define NLOC 469
#define NCLS 80
#define NFLAT 37520
#define TOPK 1000
#define NB 512           // compact hist: valid bin (o>>17) in [24230,24511] subset of [BOFF,BOFF+511]
#define BOFF 24192
#define CAP 2048         // candidate capacity

typedef unsigned long long u64;

__device__ __forceinline__ float sigm(float x) { return 1.0f / (1.0f + expf(-x)); }

// order-preserving float -> uint32 (greater float => greater uint)
__device__ __forceinline__ uint32_t f2o(float f) {
    uint32_t u = __float_as_uint(f);
    return (u & 0x80000000u) ? ~u : (u | 0x80000000u);
}

// ------------------------------------------- K1: decode (parallel, 147 blocks)
// writes o32[t]: order-preserving score value; 0 = invalid (below threshold)
__global__ void decode_kernel(
    const float* __restrict__ s0, const float* __restrict__ l0, const float* __restrict__ c0,
    const float* __restrict__ s1, const float* __restrict__ l1, const float* __restrict__ c1,
    const float* __restrict__ s2, const float* __restrict__ l2, const float* __restrict__ c2,
    uint32_t* __restrict__ o32, float4* __restrict__ bbox)
{
    int t = blockIdx.x * blockDim.x + threadIdx.x;
    if (t < NFLAT) {
        int p = t / NCLS;
        int k = t - p * NCLS;
        int c = k + 1;                       // class channel (0 = background, dropped)
        const float* sr; const float* cr; int local, hw;
        if (p < 350)      { sr = s0; cr = c0; local = p;       hw = 350; }
        else if (p < 441) { sr = s1; cr = c1; local = p - 350; hw = 91;  }
        else              { sr = s2; cr = c2; local = p - 441; hw = 28;  }
        float val = sqrtf(sigm(sr[c * hw + local]) * sigm(cr[local]));
        bool valid = (val >= 0.05f);
        // valid o in [f2o(0.05), f2o(1)) -> bin (o>>17) in [24230, 24511]
        o32[t] = valid ? f2o(val) : 0u;
    }
    if (t < NLOC) {
        int p = t;
        const float* lr; int local, hw, w; float is;
        if (p < 350)      { lr = l0; local = p;       hw = 350; w = 25; is = 16.0f; }
        else if (p < 441) { lr = l1; local = p - 350; hw = 91;  w = 13; is = 32.0f; }
        else              { lr = l2; local = p - 441; hw = 28;  w = 7;  is = 64.0f; }
        int y = local / w, x = local - y * w;
        float px = ((float)x + 0.5f) * is;
        float py = ((float)y + 0.5f) * is;
        float L = lr[local] * is;
        float T = lr[hw + local] * is;
        float R = lr[2 * hw + local] * is;
        float B = lr[3 * hw + local] * is;
        bbox[p] = make_float4(px - L, py - T, px + R, py + B);
    }
}

// ---------- K2: fused top-k (A) + pair-symmetric NMS (C), one 1024-thread block
__global__ void __launch_bounds__(1024, 4) fused_kernel(
    const uint32_t* __restrict__ o32, const float4* __restrict__ bbox,
    float* __restrict__ out)
{
    // overlay: A uses histW(32K)+histS(2K)+candL(16K) = 50K; C uses smask 128K
    __shared__ __align__(16) unsigned char ubuf[131072];
    int*      histW = (int*)ubuf;                    // 16*512 ints
    int*      histS = (int*)(ubuf + 65536);          // 512 ints (inside ubuf, after histW)
    u64*      candL = (u64*)(ubuf + 69632);          // 2048 u64
    uint32_t* smask = (uint32_t*)ubuf;               // 32000 u32 (phase C)

    __shared__ float4 sboxL[TOPK];                  // 16000 B
    __shared__ float tvalL[TOPK];
    __shared__ int   tidxL[TOPK];
    __shared__ unsigned char lab8[TOPK];
    __shared__ unsigned char zrow[TOPK];
    __shared__ unsigned short csorted[TOPK];
    __shared__ int clsStart[NCLS], clsCur[NCLS];
    __shared__ uint32_t skeep32[32], validw32[32], zmaskL[32];
    __shared__ float redMax[16], redMin[16];
    __shared__ float Mp1_s;
    __shared__ int dmax_s;
    __shared__ int bstar_s;

    int tid = threadIdx.x;
    int lane = tid & 63, wv = tid >> 6;

    // ---- A0: register-batch prefetch of o values (37520 = 36*1024 + 656)
    const int nw = (tid < 656) ? 37 : 36;
    uint32_t vbuf[37];
    #pragma unroll
    for (int k = 0; k < 37; ++k) {
        int t = tid + (k << 10);
        if (t < NFLAT) vbuf[k] = o32[t];
    }
    if (tid == 0) bstar_s = 0;
    if (tid < TOPK) { tvalL[tid] = -1.0f; tidxL[tid] = 0; }
    for (int z = tid; z < 16 * NB; z += 1024) histW[z] = 0;
    __syncthreads();
    // ---- A2: per-wave hist build from registers (valid-only; 0 skipped)
    int* myh = &histW[wv * NB];
    #pragma unroll
    for (int k = 0; k < 37; ++k) {
        if (k < nw) {
            uint32_t o = vbuf[k];
            if (o) atomicAdd(&myh[(o >> 17) - BOFF], 1);
        }
    }
    __syncthreads();
    // ---- A2b: reduce 16 sub-hists
    if (tid < NB) {
        int s = 0;
        #pragma unroll
        for (int w = 0; w < 16; ++w) s += histW[w * NB + tid];
        histS[tid] = s;
    }
    __syncthreads();
    // ---- A3: single-wave select over 512 bins
    if (tid < 64) {
        int bs = NB - 8 * (tid + 1);                // lane 0 owns HIGHEST 8 bins
        int h[8];
        int s = 0;
        #pragma unroll
        for (int k = 0; k < 8; ++k) { h[k] = histS[bs + k]; s += h[k]; }
        int ws = s;
        #pragma unroll
        for (int d = 1; d < 64; d <<= 1) {
            int v = __shfl_up(ws, d, 64);
            if (tid >= d) ws += v;
        }
        int cumAbove = ws - s;
        if (cumAbove < TOPK && ws >= TOPK) {        // exactly one lane crosses
            int running = cumAbove;
            #pragma unroll
            for (int k = 7; k >= 0; --k) {
                if (running + h[k] >= TOPK) { bstar_s = BOFF + bs + k; break; }
                running += h[k];
            }
        }
        int run = cumAbove;                         // starts, descending bin-major
        #pragma unroll
        for (int k = 7; k >= 0; --k) { histS[bs + k] = run; run += h[k]; }
    }
    __syncthreads();
    int Bstar = bstar_s;
    // ---- A4: counting-sort scatter; key rebuilt from register o and t
    #pragma unroll
    for (int k = 0; k < 37; ++k) {
        if (k < nw) {
            uint32_t o = vbuf[k];
            int b = (int)(o >> 17);
            if (o && b >= Bstar) {
                int t = tid + (k << 10);
                int pos = atomicAdd(&histS[b - BOFF], 1);
                if (pos < CAP)
                    candL[pos] = ((u64)o << 32) | (u64)(0xFFFFFFFFu - (uint32_t)t);
            }
        }
    }
    __syncthreads();
    int C = min(histS[Bstar - BOFF], CAP);          // end(Bstar) == candidate count
    // ---- A5: exact rank within bin segment -> tvalL/tidxL (LDS)
    for (int p = tid; p < C; p += 1024) {
        u64 kk = candL[p];
        int bidx = (int)(kk >> 49) - BOFF;
        int segL = (bidx == NB - 1) ? 0 : min(histS[bidx + 1], CAP);
        int segR = min(histS[bidx], CAP);
        int cnt = segL;
        for (int q = segL; q < segR; ++q)
            cnt += (candL[q] > kk) ? 1 : 0;
        if (cnt < TOPK) {
            uint32_t o = (uint32_t)(kk >> 32);
            uint32_t u = (o & 0x80000000u) ? (o ^ 0x80000000u) : ~o;  // inverse f2o
            tvalL[cnt] = __uint_as_float(u);
            tidxL[cnt] = (int)(0xFFFFFFFFu - (uint32_t)(kk & 0xFFFFFFFFu));
        }
    }
    __syncthreads();

    // ---- C: NMS (r18-proven). Load per-thread state from LDS.
    float tvR = (tid < TOPK) ? tvalL[tid] : -1.0f;
    int   idxR = (tid < TOPK) ? tidxL[tid] : 0;
    int   pR = idxR / NCLS;
    int   labR = idxR - pR * NCLS;
    float4 bR = make_float4(0.f, 0.f, 0.f, 0.f);
    if (tid < TOPK) bR = bbox[pR];

    // C1a: zero smask (vectorized, overwrites A's ubuf) + zrow
    {
        uint4* z4 = (uint4*)smask;
        for (int z = tid; z < TOPK * 8; z += 1024) z4[z] = make_uint4(0, 0, 0, 0);
    }
    if (tid < TOPK) zrow[tid] = 0;
    float m = -3.0e38f, lmin = 3.0e38f;
    if (tid < TOPK) {
        sboxL[tid] = bR;                     // raw for now
        lab8[tid] = (unsigned char)labR;
        m = fmaxf(fmaxf(bR.x, bR.y), fmaxf(bR.z, bR.w));
        lmin = fminf(bR.x, bR.y);
    }
    for (int o = 32; o > 0; o >>= 1) {
        m = fmaxf(m, __shfl_down(m, o, 64));
        lmin = fminf(lmin, __shfl_down(lmin, o, 64));
    }
    if (lane == 0) { redMax[wv] = m; redMin[wv] = lmin; }
    if (tid < NCLS) clsCur[tid] = 0;
    __syncthreads();
    if (tid == 0) {
        float mm = redMax[0], ll = redMin[0];
        for (int q = 1; q < 16; ++q) { mm = fmaxf(mm, redMax[q]); ll = fminf(ll, redMin[q]); }
        float Mp1 = mm + 1.0f;
        Mp1_s = Mp1;
        int dm = 79;
        if (Mp1 > 0.0f) {
            float ratio = (mm - ll) / Mp1;
            dm = (int)ceilf(ratio);
            if (dm < 0) dm = 0;
            if (dm > 79) dm = 79;
        }
        dmax_s = dm;
    }
    __syncthreads();
    // C1b: apply class offset in place; count classes
    float Mp1 = Mp1_s;
    if (tid < TOPK) {
        float off = (float)labR * Mp1;
        sboxL[tid] = make_float4(bR.x + off, bR.y + off, bR.z + off, bR.w + off);
        atomicAdd(&clsCur[labR], 1);
    }
    __syncthreads();
    // C2: single-wave exclusive scan of 80 class counts
    if (tid < 64) {
        int l = tid;
        int e0 = clsCur[l];
        int e1 = (l < 16) ? clsCur[64 + l] : 0;
        int s = e0;
        for (int d = 1; d < 64; d <<= 1) {
            int v = __shfl_up(s, d, 64);
            if (l >= d) s += v;
        }
        int tot64 = __shfl(s, 63, 64);
        int s2 = e1;
        for (int d = 1; d < 16; d <<= 1) {
            int v = __shfl_up(s2, d, 64);
            if (l >= d) s2 += v;
        }
        int ex0 = s - e0;
        clsStart[l] = ex0;
        clsCur[l] = ex0;
        if (l < 16) {
            int ex1 = tot64 + s2 - e1;
            clsStart[64 + l] = ex1;
            clsCur[64 + l] = ex1;
        }
    }
    __syncthreads();
    if (tid < TOPK) {
        int pos = atomicAdd(&clsCur[labR], 1);
        csorted[pos] = (unsigned short)tid;
    }
    __syncthreads();                         // clsCur[c] is now END of class c
    // C3: pair-symmetric IoU — each unordered pair computed exactly once
    if (tid < TOPK) {
        int s = tid;
        int i = csorted[s];
        int c = lab8[i];
        float4 si = sboxL[i];
        float ai = fmaxf(si.z - si.x, 0.f) * fmaxf(si.w - si.y, 0.f);
        int chi = c + dmax_s; if (chi > NCLS - 1) chi = NCLS - 1;
        int endPos = clsCur[chi];            // contiguous end through class chi
        for (int t = s + 1; t < endPos; ++t) {
            int j = csorted[t];
            float4 sj = sboxL[j];
            float aj = fmaxf(sj.z - sj.x, 0.f) * fmaxf(sj.w - sj.y, 0.f);
            float ltx = fmaxf(si.x, sj.x), lty = fmaxf(si.y, sj.y);
            float rbx = fminf(si.z, sj.z), rby = fminf(si.w, sj.w);
            float iw = fmaxf(rbx - ltx, 0.f), ih = fmaxf(rby - lty, 0.f);
            float inter = iw * ih;
            float iou = inter / fmaxf(ai + aj - inter, 1e-9f);
            if (iou > 0.6f) {
                int lo = min(i, j), hi = max(i, j);
                atomicOr(&smask[lo * 32 + (hi >> 5)], 1u << (hi & 31));
                zrow[lo] = 1;                // benign race: all writers store 1
            }
        }
    }
    __syncthreads();
    // zmask + validw ballots (row-indexed)
    {
        u64 zb = __ballot(tid < TOPK && zrow[tid] != 0);
        if (lane == 0) {
            zmaskL[wv * 2]     = (uint32_t)zb;
            zmaskL[wv * 2 + 1] = (uint32_t)(zb >> 32);
        }
        u64 bal = __ballot(tid < TOPK && tvR >= 0.05f);
        if (lane == 0) {
            validw32[wv * 2]     = (uint32_t)bal;
            validw32[wv * 2 + 1] = (uint32_t)(bal >> 32);
        }
    }
    __syncthreads();
    // C4: sparse greedy scan (single wave, 3-deep rotating prefetch)
    if (tid < 32) {
        const int ln = tid;
        uint32_t vwreg = validw32[ln];
        uint32_t zreg  = zmaskL[ln];
        uint32_t sup = 0;
        for (int wc = 0; wc < 32; ++wc) {
            uint32_t nzw = (uint32_t)__builtin_amdgcn_readlane((int)zreg, wc);
            uint32_t avail = (uint32_t)__builtin_amdgcn_readlane((int)vwreg, wc)
                           & ~(uint32_t)__builtin_amdgcn_readlane((int)sup, wc);
            int p0 = -1, p1 = -1, p2 = -1;
            uint32_t R0 = 0, R1 = 0, R2 = 0;
            if (nzw) { p0 = __ffs(nzw) - 1; nzw &= nzw - 1;
                       R0 = smask[(wc * 32 + p0) * 32 + ln]; }
            if (nzw) { p1 = __ffs(nzw) - 1; nzw &= nzw - 1;
                       R1 = smask[(wc * 32 + p1) * 32 + ln]; }
            if (nzw) { p2 = __ffs(nzw) - 1; nzw &= nzw - 1;
                       R2 = smask[(wc * 32 + p2) * 32 + ln]; }
            while (p0 >= 0) {
                uint32_t rc = (uint32_t)__builtin_amdgcn_readlane((int)R0, wc);
                uint32_t kp = (avail >> p0) & 1u;
                uint32_t mm = 0u - kp;
                sup   |= R0 & mm;
                avail &= ~(rc & mm);
                p0 = p1; R0 = R1; p1 = p2; R1 = R2;
                if (nzw) { p2 = __ffs(nzw) - 1; nzw &= nzw - 1;
                           R2 = smask[(wc * 32 + p2) * 32 + ln]; }
                else p2 = -1;
            }
            if (ln == 0) skeep32[wc] = avail;   // frozen == final keep bits
        }
    }
    __syncthreads();
    // C5: clip + output (bR/tvR/labR live in registers)
    if (tid < TOPK) {
        bool kp = (skeep32[tid >> 5] >> (tid & 31)) & 1u;
        float x1 = fminf(fmaxf(bR.x, 0.f), 224.f);
        float y1 = fminf(fmaxf(bR.y, 0.f), 398.f);
        float x2 = fminf(fmaxf(bR.z, 0.f), 224.f);
        float y2 = fminf(fmaxf(bR.w, 0.f), 398.f);
        kp = kp && ((x2 - x1) >= 1e-5f) && ((y2 - y1) >= 1e-5f);
        out[tid * 4 + 0] = kp ? x1 : 0.f;
        out[tid * 4 + 1] = kp ? y1 : 0.f;
        out[tid * 4 + 2] = kp ? x2 : 0.f;
        out[tid * 4 + 3] = kp ? y2 : 0.f;
        out[4 * TOPK + tid] = kp ? tvR : -1.0f;
        out[5 * TOPK + tid] = (float)labR;
        out[6 * TOPK + tid] = kp ? 1.0f : 0.0f;
    }
}

extern "C" void kernel_launch(void* const* d_in, const int* in_sizes, int n_in,
                              void* d_out, int out_size, void* d_ws, size_t ws_size,
                              hipStream_t stream)
{
    const float* s0 = (const float*)d_in[0];
    const float* l0 = (const float*)d_in[1];
    const float* c0 = (const float*)d_in[2];
    const float* s1 = (const float*)d_in[3];
    const float* l1 = (const float*)d_in[4];
    const float* c1 = (const float*)d_in[5];
    const float* s2 = (const float*)d_in[6];
    const float* l2 = (const float*)d_in[7];
    const float* c2 = (const float*)d_in[8];

    uint8_t* ws = (uint8_t*)d_ws;
    uint32_t* o32  = (uint32_t*)(ws);          // 37520*4 = 150080 B
    float4*   bbox = (float4*)  (ws + 150080); // 469*16  =   7504 B -> 157584 B total

    decode_kernel<<<dim3((NFLAT + 255) / 256), 256, 0, stream>>>(
        s0, l0, c0, s1, l1, c1, s2, l2, c2, o32, bbox);
    fused_kernel<<<1, 1024, 0, stream>>>(o32, bbox, (float*)d_out);
}